// Round 1
// baseline (359.098 us; speedup 1.0000x reference)
//
#include <hip/hip_runtime.h>

typedef __bf16 bf16;
typedef bf16 bf16x8 __attribute__((ext_vector_type(8)));
typedef float f32x4 __attribute__((ext_vector_type(4)));

#define MFMA16(a,b,c) __builtin_amdgcn_mfma_f32_16x16x32_bf16(a,b,c,0,0,0)

#define NSEQ 3136
#define CDIM 192

__device__ inline bf16x8 cvt8(float4 a, float4 b) {
  bf16x8 r;
  r[0]=(bf16)a.x; r[1]=(bf16)a.y; r[2]=(bf16)a.z; r[3]=(bf16)a.w;
  r[4]=(bf16)b.x; r[5]=(bf16)b.y; r[6]=(bf16)b.z; r[7]=(bf16)b.w;
  return r;
}

// ---------------- weight conversion fp32 -> bf16 ----------------
__global__ void k_convert(const float* __restrict__ qkv_w, const float* __restrict__ E_w,
                          const float* __restrict__ F_w, const float* __restrict__ proj_w,
                          bf16* __restrict__ qkvw, bf16* __restrict__ EF, bf16* __restrict__ projw) {
  int i = blockIdx.x * blockDim.x + threadIdx.x;
  const int tot = 950272;
  for (; i < tot; i += gridDim.x * blockDim.x) {
    if (i < 110592) qkvw[i] = (bf16)qkv_w[i];
    else if (i < 512000) EF[i - 110592] = (bf16)E_w[i - 110592];
    else if (i < 913408) EF[i - 110592] = (bf16)F_w[i - 512000];
    else projw[i - 913408] = (bf16)proj_w[i - 913408];
  }
}

// rowsums[kr] = sum_n E_w[kr,n] (kr<128) or F_w[kr-128,n]
__global__ void k_rowsum(const float* __restrict__ E_w, const float* __restrict__ F_w,
                         float* __restrict__ rowsums) {
  int row = blockIdx.x; // 0..255
  const float* src = (row < 128) ? (E_w + (long)row * NSEQ) : (F_w + (long)(row - 128) * NSEQ);
  float s = 0.f;
  for (int i = threadIdx.x; i < NSEQ; i += 64) s += src[i];
  for (int off = 32; off; off >>= 1) s += __shfl_xor(s, off);
  if (threadIdx.x == 0) rowsums[row] = s;
}

// ---------------- window_reverse + transpose: x (2048,49,192) f32 -> xmT (32,192,3136) bf16 --------
__global__ void k_xT(const float* __restrict__ x, bf16* __restrict__ xmT) {
  __shared__ bf16 tile[32][200];
  int blk = blockIdx.x;
  int b = blk / 98, n0 = (blk % 98) * 32;
  int c = threadIdx.x; // 0..191
  for (int i = 0; i < 32; ++i) {
    int n = n0 + i;
    int r = n / 56, cc = n % 56;
    long srcrow = ((long)(b * 64 + (r / 7) * 8 + (cc / 7)) * 49 + (r % 7) * 7 + (cc % 7));
    tile[i][c] = (bf16)x[srcrow * 192 + c];
  }
  __syncthreads();
  int nn = threadIdx.x & 31;
  int cb = threadIdx.x >> 5; // 0..5
  for (int i = 0; i < 32; ++i) {
    int c2 = cb + 6 * i;
    xmT[((long)b * 192 + c2) * NSEQ + n0 + nn] = tile[nn][c2];
  }
}

// ---------------- Q GEMM: q(g,192) = window_reverse(x)(g,192) @ Wq^T, +bias, *scale, bf16 out -----
__launch_bounds__(256)
__global__ void k_qgemm(const float* __restrict__ x, const bf16* __restrict__ qkvw,
                        const float* __restrict__ qkv_b, bf16* __restrict__ q) {
  __shared__ bf16 As[128][40];
  __shared__ bf16 Bs[64][40];
  int bn = blockIdx.x % 3;
  long g0 = (long)(blockIdx.x / 3) * 128;
  int n0 = bn * 64;
  int tid = threadIdx.x;
  int wid = tid >> 6, lane = tid & 63;
  int wm = wid >> 1, wn = wid & 1;
  int lrow = lane & 15, lk = (lane >> 4) * 8;
  // A staging: 2 threads per row, 16 f32 each, gather via window_reverse map
  int arow = tid >> 1, akoff = (tid & 1) * 16;
  long g = g0 + arow;
  int b = (int)(g / NSEQ), n = (int)(g % NSEQ);
  int r = n / 56, cc = n % 56;
  long srcrow = (long)(b * 64 + (r / 7) * 8 + (cc / 7)) * 49 + (r % 7) * 7 + (cc % 7);
  const float* Ap = x + srcrow * 192 + akoff;
  int brow = tid >> 2, bkoff = (tid & 3) * 8;
  const bf16* Bp = qkvw + (long)(n0 + brow) * 192 + bkoff; // Wq rows 0..191
  f32x4 zero = {0.f, 0.f, 0.f, 0.f};
  f32x4 acc[4][2];
  for (int i = 0; i < 4; i++) for (int j = 0; j < 2; j++) acc[i][j] = zero;
  for (int k0 = 0; k0 < 192; k0 += 32) {
    const float4* xp = (const float4*)(Ap + k0);
    float4 f0 = xp[0], f1 = xp[1], f2 = xp[2], f3 = xp[3];
    *(bf16x8*)&As[arow][akoff] = cvt8(f0, f1);
    *(bf16x8*)&As[arow][akoff + 8] = cvt8(f2, f3);
    *(bf16x8*)&Bs[brow][bkoff] = *(const bf16x8*)(Bp + k0);
    __syncthreads();
    bf16x8 af[4], bfv[2];
    for (int i = 0; i < 4; i++) af[i] = *(bf16x8*)&As[wm * 64 + 16 * i + lrow][lk];
    for (int j = 0; j < 2; j++) bfv[j] = *(bf16x8*)&Bs[wn * 32 + 16 * j + lrow][lk];
    for (int i = 0; i < 4; i++) for (int j = 0; j < 2; j++) acc[i][j] = MFMA16(af[i], bfv[j], acc[i][j]);
    __syncthreads();
  }
  const float scale = 0.17677669529663687f; // 1/sqrt(32)
  for (int i = 0; i < 4; i++) for (int j = 0; j < 2; j++) for (int rr = 0; rr < 4; rr++) {
    long grow = g0 + wm * 64 + 16 * i + (lane >> 4) * 4 + rr;
    int c = n0 + wn * 32 + 16 * j + lrow;
    float v = (acc[i][j][rr] + qkv_b[c]) * scale;
    q[grow * 192 + c] = (bf16)v;
  }
}

// ---------------- xlow GEMM: el_fl(b,256,192) = [E;F](256,3136) @ xmT(b,192,3136)^T ----------------
__launch_bounds__(256)
__global__ void k_xlow(const bf16* __restrict__ EF, const bf16* __restrict__ xmT,
                       bf16* __restrict__ el_fl) {
  __shared__ bf16 As[64][40];
  __shared__ bf16 Bs[64][40];
  int idx = blockIdx.x;
  int b = idx / 12, rem = idx % 12;
  int m0 = (rem / 3) * 64, n0 = (rem % 3) * 64;
  int tid = threadIdx.x;
  int wid = tid >> 6, lane = tid & 63;
  int wm = wid >> 1, wn = wid & 1;
  int lrow = lane & 15, lk = (lane >> 4) * 8;
  int srow = tid >> 2, skoff = (tid & 3) * 8;
  const bf16* Ap = EF + (long)(m0 + srow) * NSEQ + skoff;
  const bf16* Bp = xmT + ((long)b * 192 + n0 + srow) * NSEQ + skoff;
  f32x4 zero = {0.f, 0.f, 0.f, 0.f};
  f32x4 acc[2][2];
  for (int i = 0; i < 2; i++) for (int j = 0; j < 2; j++) acc[i][j] = zero;
  for (int k0 = 0; k0 < NSEQ; k0 += 32) {
    *(bf16x8*)&As[srow][skoff] = *(const bf16x8*)(Ap + k0);
    *(bf16x8*)&Bs[srow][skoff] = *(const bf16x8*)(Bp + k0);
    __syncthreads();
    bf16x8 af[2], bfv[2];
    for (int i = 0; i < 2; i++) af[i] = *(bf16x8*)&As[wm * 32 + 16 * i + lrow][lk];
    for (int j = 0; j < 2; j++) bfv[j] = *(bf16x8*)&Bs[wn * 32 + 16 * j + lrow][lk];
    for (int i = 0; i < 2; i++) for (int j = 0; j < 2; j++) acc[i][j] = MFMA16(af[i], bfv[j], acc[i][j]);
    __syncthreads();
  }
  for (int i = 0; i < 2; i++) for (int j = 0; j < 2; j++) for (int rr = 0; rr < 4; rr++) {
    int kr = m0 + wm * 32 + 16 * i + (lane >> 4) * 4 + rr;
    int c = n0 + wn * 32 + 16 * j + lrow;
    el_fl[((long)b * 256 + kr) * 192 + c] = (bf16)acc[i][j][rr];
  }
}

// ---------------- low-rank proj: k_low(b,128,192) = el@Wk^T + bias ; v_lowT(b,192,128) = Wv@fl^T + bias
__launch_bounds__(256)
__global__ void k_lowproj(const bf16* __restrict__ el_fl, const bf16* __restrict__ qkvw,
                          const float* __restrict__ qkv_b, const float* __restrict__ E_b,
                          const float* __restrict__ F_b, const float* __restrict__ rowsums,
                          bf16* __restrict__ k_low, bf16* __restrict__ v_lowT) {
  __shared__ bf16 As[64][40];
  __shared__ bf16 Bs[64][40];
  int idx = blockIdx.x;
  int b = idx / 12, rem = idx % 12;
  int type = rem / 6; rem %= 6;
  int bm, bn;
  if (type == 0) { bm = rem / 3; bn = rem % 3; } // M=128 (kr), N=192 (c)
  else           { bm = rem / 2; bn = rem % 2; } // M=192 (c),  N=128 (kr)
  int m0 = bm * 64, n0 = bn * 64;
  int tid = threadIdx.x;
  int wid = tid >> 6, lane = tid & 63;
  int wm = wid >> 1, wn = wid & 1;
  int lrow = lane & 15, lk = (lane >> 4) * 8;
  int srow = tid >> 2, skoff = (tid & 3) * 8;
  const bf16* Ap; const bf16* Bp;
  if (type == 0) {
    Ap = el_fl + ((long)b * 256 + m0 + srow) * 192 + skoff;       // el rows (kr)
    Bp = qkvw + (long)(192 + n0 + srow) * 192 + skoff;            // Wk rows (c)
  } else {
    Ap = qkvw + (long)(384 + m0 + srow) * 192 + skoff;            // Wv rows (c)
    Bp = el_fl + ((long)b * 256 + 128 + n0 + srow) * 192 + skoff; // fl rows (kr)
  }
  f32x4 zero = {0.f, 0.f, 0.f, 0.f};
  f32x4 acc[2][2];
  for (int i = 0; i < 2; i++) for (int j = 0; j < 2; j++) acc[i][j] = zero;
  for (int k0 = 0; k0 < 192; k0 += 32) {
    *(bf16x8*)&As[srow][skoff] = *(const bf16x8*)(Ap + k0);
    *(bf16x8*)&Bs[srow][skoff] = *(const bf16x8*)(Bp + k0);
    __syncthreads();
    bf16x8 af[2], bfv[2];
    for (int i = 0; i < 2; i++) af[i] = *(bf16x8*)&As[wm * 32 + 16 * i + lrow][lk];
    for (int j = 0; j < 2; j++) bfv[j] = *(bf16x8*)&Bs[wn * 32 + 16 * j + lrow][lk];
    for (int i = 0; i < 2; i++) for (int j = 0; j < 2; j++) acc[i][j] = MFMA16(af[i], bfv[j], acc[i][j]);
    __syncthreads();
  }
  if (type == 0) {
    for (int i = 0; i < 2; i++) for (int j = 0; j < 2; j++) for (int rr = 0; rr < 4; rr++) {
      int kr = m0 + wm * 32 + 16 * i + (lane >> 4) * 4 + rr;
      int c = n0 + wn * 32 + 16 * j + lrow;
      float v = acc[i][j][rr] + rowsums[kr] * qkv_b[192 + c] + E_b[kr];
      k_low[((long)b * 128 + kr) * 192 + c] = (bf16)v;
    }
  } else {
    for (int i = 0; i < 2; i++) for (int j = 0; j < 2; j++) for (int rr = 0; rr < 4; rr++) {
      int c = m0 + wm * 32 + 16 * i + (lane >> 4) * 4 + rr;
      int kr = n0 + wn * 32 + 16 * j + lrow;
      float v = acc[i][j][rr] + rowsums[128 + kr] * qkv_b[384 + c] + F_b[kr];
      v_lowT[((long)b * 192 + c) * 128 + kr] = (bf16)v;
    }
  }
}

// ---------------- fused attention: per (b,h,64-row tile): S = q@k_low^T, softmax, O = P@v_low -----
__launch_bounds__(256)
__global__ void k_attn(const bf16* __restrict__ q, const bf16* __restrict__ k_low,
                       const bf16* __restrict__ v_lowT, bf16* __restrict__ out_att) {
  __shared__ bf16 Ks[128][40];
  __shared__ bf16 Vs[32][136];
  __shared__ bf16 Ps[4][16][136];
  int idx = blockIdx.x;
  int nt = idx % 49, bh = idx / 49;
  int h = bh % 6, b = bh / 6;
  int n0 = nt * 64;
  int tid = threadIdx.x;
  int wid = tid >> 6, lane = tid & 63;
  int lrow = lane & 15, lk = (lane >> 4) * 8;
  // stage k_low head slice (128 x 32)
  {
    int row = tid >> 1, koff = (tid & 1) * 16;
    const bf16* src = k_low + ((long)b * 128 + row) * 192 + h * 32 + koff;
    *(bf16x8*)&Ks[row][koff] = *(const bf16x8*)src;
    *(bf16x8*)&Ks[row][koff + 8] = *(const bf16x8*)(src + 8);
  }
  // stage v_lowT head slice (32 x 128)
  {
    int row = tid >> 3, koff = (tid & 7) * 16;
    const bf16* src = v_lowT + ((long)b * 192 + h * 32 + row) * 128 + koff;
    *(bf16x8*)&Vs[row][koff] = *(const bf16x8*)src;
    *(bf16x8*)&Vs[row][koff + 8] = *(const bf16x8*)(src + 8);
  }
  // q fragment (A-operand), 16 rows per wave, K=32=head_dim
  int nrow = n0 + wid * 16 + lrow;
  bf16x8 qf = *(const bf16x8*)(q + ((long)b * NSEQ + nrow) * 192 + h * 32 + lk);
  __syncthreads();
  f32x4 zero = {0.f, 0.f, 0.f, 0.f};
  f32x4 s[8];
  for (int f = 0; f < 8; f++) {
    bf16x8 kf = *(bf16x8*)&Ks[16 * f + lrow][lk];
    s[f] = MFMA16(qf, kf, zero);
  }
  // softmax over 128 cols; row = (lane>>4)*4+rr, cols = 16f+lrow (q already scaled)
  for (int rr = 0; rr < 4; rr++) {
    float m = s[0][rr];
    for (int f = 1; f < 8; f++) m = fmaxf(m, s[f][rr]);
    for (int off = 1; off < 16; off <<= 1) m = fmaxf(m, __shfl_xor(m, off));
    float sum = 0.f;
    for (int f = 0; f < 8; f++) { float p = __expf(s[f][rr] - m); s[f][rr] = p; sum += p; }
    for (int off = 1; off < 16; off <<= 1) sum += __shfl_xor(sum, off);
    float inv = 1.0f / sum;
    for (int f = 0; f < 8; f++) s[f][rr] *= inv;
  }
  // C-layout -> A-layout via LDS
  for (int f = 0; f < 8; f++)
    for (int rr = 0; rr < 4; rr++)
      Ps[wid][(lane >> 4) * 4 + rr][16 * f + lrow] = (bf16)s[f][rr];
  __syncthreads();
  f32x4 o[2];
  o[0] = zero; o[1] = zero;
  for (int ks = 0; ks < 4; ks++) {
    bf16x8 pf = *(bf16x8*)&Ps[wid][lrow][ks * 32 + lk];
    for (int j = 0; j < 2; j++) {
      bf16x8 vf = *(bf16x8*)&Vs[16 * j + lrow][ks * 32 + lk];
      o[j] = MFMA16(pf, vf, o[j]);
    }
  }
  for (int j = 0; j < 2; j++) for (int rr = 0; rr < 4; rr++) {
    int nn = n0 + wid * 16 + (lane >> 4) * 4 + rr;
    out_att[((long)b * NSEQ + nn) * 192 + h * 32 + 16 * j + lrow] = (bf16)o[j][rr];
  }
}

// ---------------- proj GEMM: out(g,192) f32 = out_att(g,192) @ proj_w^T + proj_b -------------------
__launch_bounds__(256)
__global__ void k_proj(const bf16* __restrict__ oa, const bf16* __restrict__ projw,
                       const float* __restrict__ proj_b, float* __restrict__ out) {
  __shared__ bf16 As[128][40];
  __shared__ bf16 Bs[64][40];
  int bn = blockIdx.x % 3;
  long g0 = (long)(blockIdx.x / 3) * 128;
  int n0 = bn * 64;
  int tid = threadIdx.x;
  int wid = tid >> 6, lane = tid & 63;
  int wm = wid >> 1, wn = wid & 1;
  int lrow = lane & 15, lk = (lane >> 4) * 8;
  int arow = tid >> 1, akoff = (tid & 1) * 16;
  const bf16* Ap = oa + (g0 + arow) * 192 + akoff;
  int brow = tid >> 2, bkoff = (tid & 3) * 8;
  const bf16* Bp = projw + (long)(n0 + brow) * 192 + bkoff;
  f32x4 zero = {0.f, 0.f, 0.f, 0.f};
  f32x4 acc[4][2];
  for (int i = 0; i < 4; i++) for (int j = 0; j < 2; j++) acc[i][j] = zero;
  for (int k0 = 0; k0 < 192; k0 += 32) {
    *(bf16x8*)&As[arow][akoff] = *(const bf16x8*)(Ap + k0);
    *(bf16x8*)&As[arow][akoff + 8] = *(const bf16x8*)(Ap + k0 + 8);
    *(bf16x8*)&Bs[brow][bkoff] = *(const bf16x8*)(Bp + k0);
    __syncthreads();
    bf16x8 af[4], bfv[2];
    for (int i = 0; i < 4; i++) af[i] = *(bf16x8*)&As[wm * 64 + 16 * i + lrow][lk];
    for (int j = 0; j < 2; j++) bfv[j] = *(bf16x8*)&Bs[wn * 32 + 16 * j + lrow][lk];
    for (int i = 0; i < 4; i++) for (int j = 0; j < 2; j++) acc[i][j] = MFMA16(af[i], bfv[j], acc[i][j]);
    __syncthreads();
  }
  for (int i = 0; i < 4; i++) for (int j = 0; j < 2; j++) for (int rr = 0; rr < 4; rr++) {
    long grow = g0 + wm * 64 + 16 * i + (lane >> 4) * 4 + rr;
    int c = n0 + wn * 32 + 16 * j + lrow;
    out[grow * 192 + c] = acc[i][j][rr] + proj_b[c];
  }
}

extern "C" void kernel_launch(void* const* d_in, const int* in_sizes, int n_in,
                              void* d_out, int out_size, void* d_ws, size_t ws_size,
                              hipStream_t stream) {
  const float* x      = (const float*)d_in[0];
  const float* qkv_w  = (const float*)d_in[1];
  const float* qkv_b  = (const float*)d_in[2];
  const float* E_w    = (const float*)d_in[3];
  const float* E_b    = (const float*)d_in[4];
  const float* F_w    = (const float*)d_in[5];
  const float* F_b    = (const float*)d_in[6];
  const float* proj_w = (const float*)d_in[7];
  const float* proj_b = (const float*)d_in[8];
  float* out = (float*)d_out;

  char* ws = (char*)d_ws;
  size_t off = 0;
  auto alloc = [&](size_t bytes) { char* p = ws + off; off += (bytes + 255) & ~(size_t)255; return p; };
  bf16* qkvw    = (bf16*)alloc((size_t)110592 * 2);
  bf16* EF      = (bf16*)alloc((size_t)802816 * 2);
  bf16* projw   = (bf16*)alloc((size_t)36864 * 2);
  float* rowsums = (float*)alloc((size_t)256 * 4);
  bf16* xmT     = (bf16*)alloc((size_t)32 * 192 * NSEQ * 2);
  bf16* q       = (bf16*)alloc((size_t)32 * NSEQ * 192 * 2);
  bf16* el_fl   = (bf16*)alloc((size_t)32 * 256 * 192 * 2);
  bf16* k_low   = (bf16*)alloc((size_t)32 * 128 * 192 * 2);
  bf16* v_lowT  = (bf16*)alloc((size_t)32 * 192 * 128 * 2);
  bf16* out_att = xmT; // xmT dead after k_xlow; reuse for out_att (written by k_attn)

  k_convert<<<dim3(480), dim3(256), 0, stream>>>(qkv_w, E_w, F_w, proj_w, qkvw, EF, projw);
  k_rowsum<<<dim3(256), dim3(64), 0, stream>>>(E_w, F_w, rowsums);
  k_xT<<<dim3(32 * 98), dim3(192), 0, stream>>>(x, xmT);
  k_qgemm<<<dim3(784 * 3), dim3(256), 0, stream>>>(x, qkvw, qkv_b, q);
  k_xlow<<<dim3(384), dim3(256), 0, stream>>>(EF, xmT, el_fl);
  k_lowproj<<<dim3(384), dim3(256), 0, stream>>>(el_fl, qkvw, qkv_b, E_b, F_b, rowsums, k_low, v_lowT);
  k_attn<<<dim3(32 * 6 * 49), dim3(256), 0, stream>>>(q, k_low, v_lowT, out_att);
  k_proj<<<dim3(784 * 3), dim3(256), 0, stream>>>(out_att, projw, proj_b, out);
}

// Round 2
// 341.367 us; speedup vs baseline: 1.0519x; 1.0519x over previous
//
#include <hip/hip_runtime.h>

typedef __bf16 bf16;
typedef bf16 bf16x8 __attribute__((ext_vector_type(8)));
typedef float f32x4 __attribute__((ext_vector_type(4)));

#define MFMA16(a,b,c) __builtin_amdgcn_mfma_f32_16x16x32_bf16(a,b,c,0,0,0)

#define NSEQ 3136
#define CDIM 192

__device__ inline bf16x8 cvt8(float4 a, float4 b) {
  bf16x8 r;
  r[0]=(bf16)a.x; r[1]=(bf16)a.y; r[2]=(bf16)a.z; r[3]=(bf16)a.w;
  r[4]=(bf16)b.x; r[5]=(bf16)b.y; r[6]=(bf16)b.z; r[7]=(bf16)b.w;
  return r;
}

// ---------------- weight conversion fp32 -> bf16 ----------------
__global__ void k_convert(const float* __restrict__ qkv_w, const float* __restrict__ E_w,
                          const float* __restrict__ F_w, const float* __restrict__ proj_w,
                          bf16* __restrict__ qkvw, bf16* __restrict__ EF, bf16* __restrict__ projw) {
  int i = blockIdx.x * blockDim.x + threadIdx.x;
  const int tot = 950272;
  for (; i < tot; i += gridDim.x * blockDim.x) {
    if (i < 110592) qkvw[i] = (bf16)qkv_w[i];
    else if (i < 512000) EF[i - 110592] = (bf16)E_w[i - 110592];
    else if (i < 913408) EF[i - 110592] = (bf16)F_w[i - 512000];
    else projw[i - 913408] = (bf16)proj_w[i - 913408];
  }
}

// rowsums[kr] = sum_n E_w[kr,n] (kr<128) or F_w[kr-128,n]
__global__ void k_rowsum(const float* __restrict__ E_w, const float* __restrict__ F_w,
                         float* __restrict__ rowsums) {
  __shared__ float red[4];
  int row = blockIdx.x; // 0..255
  const float* src = (row < 128) ? (E_w + (long)row * NSEQ) : (F_w + (long)(row - 128) * NSEQ);
  float s = 0.f;
  for (int i = threadIdx.x; i < NSEQ; i += 256) s += src[i];
  for (int off = 32; off; off >>= 1) s += __shfl_xor(s, off);
  if ((threadIdx.x & 63) == 0) red[threadIdx.x >> 6] = s;
  __syncthreads();
  if (threadIdx.x == 0) rowsums[row] = red[0] + red[1] + red[2] + red[3];
}

// ---------------- window_reverse + transpose: x (2048,49,192) f32 -> xmT (32,192,3136) bf16 --------
__global__ void k_xT(const float* __restrict__ x, bf16* __restrict__ xmT) {
  __shared__ bf16 tile[32][200];
  int blk = blockIdx.x;
  int b = blk / 98, n0 = (blk % 98) * 32;
  int c = threadIdx.x; // 0..191
  for (int i = 0; i < 32; ++i) {
    int n = n0 + i;
    int r = n / 56, cc = n % 56;
    long srcrow = ((long)(b * 64 + (r / 7) * 8 + (cc / 7)) * 49 + (r % 7) * 7 + (cc % 7));
    tile[i][c] = (bf16)x[srcrow * 192 + c];
  }
  __syncthreads();
  int nn = threadIdx.x & 31;
  int cb = threadIdx.x >> 5; // 0..5
  for (int i = 0; i < 32; ++i) {
    int c2 = cb + 6 * i;
    xmT[((long)b * 192 + c2) * NSEQ + n0 + nn] = tile[nn][c2];
  }
}

// ---------------- xlow GEMM split-K: partial[(b*12+t)*7+s] = [E;F]-tile @ xmT-tile^T over K-slice ---
__launch_bounds__(256)
__global__ void k_xlow(const bf16* __restrict__ EF, const bf16* __restrict__ xmT,
                       float* __restrict__ partial) {
  __shared__ bf16 As[64][72];
  __shared__ bf16 Bs[64][72];
  int idx = blockIdx.x;
  int s = idx % 7;
  int rem = (idx / 7) % 12;
  int b = idx / 84;
  int m0 = (rem / 3) * 64, n0 = (rem % 3) * 64;
  int kbase = s * 448;
  int tid = threadIdx.x;
  int wid = tid >> 6, lane = tid & 63;
  int wm = wid >> 1, wn = wid & 1;
  int lrow = lane & 15, lk = (lane >> 4) * 8;
  int srow = tid >> 2, skoff = (tid & 3) * 16;
  const bf16* Ap = EF + (long)(m0 + srow) * NSEQ + kbase + skoff;
  const bf16* Bp = xmT + ((long)b * 192 + n0 + srow) * NSEQ + kbase + skoff;
  f32x4 zero = {0.f, 0.f, 0.f, 0.f};
  f32x4 acc[2][2];
  for (int i = 0; i < 2; i++) for (int j = 0; j < 2; j++) acc[i][j] = zero;
  for (int k0 = 0; k0 < 448; k0 += 64) {
    *(bf16x8*)&As[srow][skoff]     = *(const bf16x8*)(Ap + k0);
    *(bf16x8*)&As[srow][skoff + 8] = *(const bf16x8*)(Ap + k0 + 8);
    *(bf16x8*)&Bs[srow][skoff]     = *(const bf16x8*)(Bp + k0);
    *(bf16x8*)&Bs[srow][skoff + 8] = *(const bf16x8*)(Bp + k0 + 8);
    __syncthreads();
    for (int ks = 0; ks < 2; ks++) {
      bf16x8 af[2], bfv[2];
      for (int i = 0; i < 2; i++) af[i]  = *(bf16x8*)&As[wm * 32 + 16 * i + lrow][ks * 32 + lk];
      for (int j = 0; j < 2; j++) bfv[j] = *(bf16x8*)&Bs[wn * 32 + 16 * j + lrow][ks * 32 + lk];
      for (int i = 0; i < 2; i++) for (int j = 0; j < 2; j++) acc[i][j] = MFMA16(af[i], bfv[j], acc[i][j]);
    }
    __syncthreads();
  }
  float* P = partial + (long)idx * 4096;
  for (int i = 0; i < 2; i++) for (int j = 0; j < 2; j++) for (int rr = 0; rr < 4; rr++) {
    int rl = wm * 32 + 16 * i + (lane >> 4) * 4 + rr;
    int cl = wn * 32 + 16 * j + lrow;
    P[rl * 64 + cl] = acc[i][j][rr];
  }
}

// ---------------- reduce 7 split-K partials -> el_fl (b,256,192) bf16 ------------------------------
__global__ void k_reduce(const float* __restrict__ partial, bf16* __restrict__ el_fl) {
  int idx = blockIdx.x;          // 32*12*4
  int qtr = idx & 3;
  int bt = idx >> 2;             // b*12 + t
  int t = bt % 12, b = bt / 12;
  const float* P = partial + (long)bt * 7 * 4096 + qtr * 1024;
  for (int i = 0; i < 4; i++) {
    int e = i * 256 + threadIdx.x;
    float sum = 0.f;
    for (int s = 0; s < 7; s++) sum += P[s * 4096 + e];
    int ee = qtr * 1024 + e;
    int lm = ee >> 6, lc = ee & 63;
    int kr = (t / 3) * 64 + lm, c = (t % 3) * 64 + lc;
    el_fl[((long)b * 256 + kr) * 192 + c] = (bf16)sum;
  }
}

// ---------------- low-rank proj: k_low = el@Wk^T + bias ; v_lowT = Wv@fl^T + bias (K=192 1-stage) --
__launch_bounds__(256)
__global__ void k_lowproj(const bf16* __restrict__ el_fl, const bf16* __restrict__ qkvw,
                          const float* __restrict__ qkv_b, const float* __restrict__ E_b,
                          const float* __restrict__ F_b, const float* __restrict__ rowsums,
                          bf16* __restrict__ k_low, bf16* __restrict__ v_lowT) {
  __shared__ bf16 As[64][200];
  __shared__ bf16 Bs[64][200];
  int idx = blockIdx.x;
  int b = idx / 12, rem = idx % 12;
  int type = rem / 6; rem %= 6;
  int bm, bn;
  if (type == 0) { bm = rem / 3; bn = rem % 3; }
  else           { bm = rem / 2; bn = rem % 2; }
  int m0 = bm * 64, n0 = bn * 64;
  int tid = threadIdx.x;
  int wid = tid >> 6, lane = tid & 63;
  int wm = wid >> 1, wn = wid & 1;
  int lrow = lane & 15, lk = (lane >> 4) * 8;
  int srow = tid >> 2, skoff = (tid & 3) * 16;
  const bf16* Ap; const bf16* Bp;
  if (type == 0) {
    Ap = el_fl + ((long)b * 256 + m0 + srow) * 192 + skoff;
    Bp = qkvw + (long)(192 + n0 + srow) * 192 + skoff;
  } else {
    Ap = qkvw + (long)(384 + m0 + srow) * 192 + skoff;
    Bp = el_fl + ((long)b * 256 + 128 + n0 + srow) * 192 + skoff;
  }
  for (int kk = 0; kk < 192; kk += 64) {
    *(bf16x8*)&As[srow][kk + skoff]     = *(const bf16x8*)(Ap + kk);
    *(bf16x8*)&As[srow][kk + skoff + 8] = *(const bf16x8*)(Ap + kk + 8);
    *(bf16x8*)&Bs[srow][kk + skoff]     = *(const bf16x8*)(Bp + kk);
    *(bf16x8*)&Bs[srow][kk + skoff + 8] = *(const bf16x8*)(Bp + kk + 8);
  }
  __syncthreads();
  f32x4 zero = {0.f, 0.f, 0.f, 0.f};
  f32x4 acc[2][2];
  for (int i = 0; i < 2; i++) for (int j = 0; j < 2; j++) acc[i][j] = zero;
  for (int ks = 0; ks < 6; ks++) {
    bf16x8 af[2], bfv[2];
    for (int i = 0; i < 2; i++) af[i]  = *(bf16x8*)&As[wm * 32 + 16 * i + lrow][ks * 32 + lk];
    for (int j = 0; j < 2; j++) bfv[j] = *(bf16x8*)&Bs[wn * 32 + 16 * j + lrow][ks * 32 + lk];
    for (int i = 0; i < 2; i++) for (int j = 0; j < 2; j++) acc[i][j] = MFMA16(af[i], bfv[j], acc[i][j]);
  }
  if (type == 0) {
    for (int i = 0; i < 2; i++) for (int j = 0; j < 2; j++) for (int rr = 0; rr < 4; rr++) {
      int kr = m0 + wm * 32 + 16 * i + (lane >> 4) * 4 + rr;
      int c = n0 + wn * 32 + 16 * j + lrow;
      float v = acc[i][j][rr] + rowsums[kr] * qkv_b[192 + c] + E_b[kr];
      k_low[((long)b * 128 + kr) * 192 + c] = (bf16)v;
    }
  } else {
    for (int i = 0; i < 2; i++) for (int j = 0; j < 2; j++) for (int rr = 0; rr < 4; rr++) {
      int c = m0 + wm * 32 + 16 * i + (lane >> 4) * 4 + rr;
      int kr = n0 + wn * 32 + 16 * j + lrow;
      float v = acc[i][j][rr] + rowsums[128 + kr] * qkv_b[384 + c] + F_b[kr];
      v_lowT[((long)b * 192 + c) * 128 + kr] = (bf16)v;
    }
  }
}

// ---------------- Q GEMM: q(g,192) = window_reverse(x)(g,192) @ Wq^T, +bias, *scale (BK=96) -------
__launch_bounds__(256)
__global__ void k_qgemm(const float* __restrict__ x, const bf16* __restrict__ qkvw,
                        const float* __restrict__ qkv_b, bf16* __restrict__ q) {
  __shared__ bf16 As[128][104];
  __shared__ bf16 Bs[64][104];
  int bn = blockIdx.x % 3;
  long g0 = (long)(blockIdx.x / 3) * 128;
  int n0 = bn * 64;
  int tid = threadIdx.x;
  int wid = tid >> 6, lane = tid & 63;
  int wm = wid >> 1, wn = wid & 1;
  int lrow = lane & 15, lk = (lane >> 4) * 8;
  int arow = tid >> 1, ahalf = (tid & 1) * 48;
  long g = g0 + arow;
  int b = (int)(g / NSEQ), n = (int)(g % NSEQ);
  int r = n / 56, cc = n % 56;
  long srcrow = (long)(b * 64 + (r / 7) * 8 + (cc / 7)) * 49 + (r % 7) * 7 + (cc % 7);
  const float* Ap = x + srcrow * 192 + ahalf;
  int brow = tid >> 2, bkoff = (tid & 3) * 24;
  const bf16* Bp = qkvw + (long)(n0 + brow) * 192 + bkoff;
  f32x4 zero = {0.f, 0.f, 0.f, 0.f};
  f32x4 acc[4][2];
  for (int i = 0; i < 4; i++) for (int j = 0; j < 2; j++) acc[i][j] = zero;
  for (int k0 = 0; k0 < 192; k0 += 96) {
    for (int m = 0; m < 3; m++) {
      const float4* xp = (const float4*)(Ap + k0 + 16 * m);
      float4 f0 = xp[0], f1 = xp[1], f2 = xp[2], f3 = xp[3];
      *(bf16x8*)&As[arow][ahalf + 16 * m]     = cvt8(f0, f1);
      *(bf16x8*)&As[arow][ahalf + 16 * m + 8] = cvt8(f2, f3);
    }
    for (int m = 0; m < 3; m++)
      *(bf16x8*)&Bs[brow][bkoff + 8 * m] = *(const bf16x8*)(Bp + k0 + 8 * m);
    __syncthreads();
    for (int ks = 0; ks < 3; ks++) {
      bf16x8 af[4], bfv[2];
      for (int i = 0; i < 4; i++) af[i]  = *(bf16x8*)&As[wm * 64 + 16 * i + lrow][ks * 32 + lk];
      for (int j = 0; j < 2; j++) bfv[j] = *(bf16x8*)&Bs[wn * 32 + 16 * j + lrow][ks * 32 + lk];
      for (int i = 0; i < 4; i++) for (int j = 0; j < 2; j++) acc[i][j] = MFMA16(af[i], bfv[j], acc[i][j]);
    }
    __syncthreads();
  }
  const float scale = 0.17677669529663687f; // 1/sqrt(32)
  for (int i = 0; i < 4; i++) for (int j = 0; j < 2; j++) for (int rr = 0; rr < 4; rr++) {
    long grow = g0 + wm * 64 + 16 * i + (lane >> 4) * 4 + rr;
    int c = n0 + wn * 32 + 16 * j + lrow;
    float v = (acc[i][j][rr] + qkv_b[c]) * scale;
    q[grow * 192 + c] = (bf16)v;
  }
}

// ---------------- fused attention: per (b,h,64-row tile): S = q@k_low^T, softmax, O = P@v_low -----
__launch_bounds__(256)
__global__ void k_attn(const bf16* __restrict__ q, const bf16* __restrict__ k_low,
                       const bf16* __restrict__ v_lowT, bf16* __restrict__ out_att) {
  __shared__ bf16 Ks[128][40];
  __shared__ bf16 Vs[32][136];
  __shared__ bf16 Ps[4][16][136];
  int idx = blockIdx.x;
  int nt = idx % 49, bh = idx / 49;
  int h = bh % 6, b = bh / 6;
  int n0 = nt * 64;
  int tid = threadIdx.x;
  int wid = tid >> 6, lane = tid & 63;
  int lrow = lane & 15, lk = (lane >> 4) * 8;
  {
    int row = tid >> 1, koff = (tid & 1) * 16;
    const bf16* src = k_low + ((long)b * 128 + row) * 192 + h * 32 + koff;
    *(bf16x8*)&Ks[row][koff] = *(const bf16x8*)src;
    *(bf16x8*)&Ks[row][koff + 8] = *(const bf16x8*)(src + 8);
  }
  {
    int row = tid >> 3, koff = (tid & 7) * 16;
    const bf16* src = v_lowT + ((long)b * 192 + h * 32 + row) * 128 + koff;
    *(bf16x8*)&Vs[row][koff] = *(const bf16x8*)src;
    *(bf16x8*)&Vs[row][koff + 8] = *(const bf16x8*)(src + 8);
  }
  int nrow = n0 + wid * 16 + lrow;
  bf16x8 qf = *(const bf16x8*)(q + ((long)b * NSEQ + nrow) * 192 + h * 32 + lk);
  __syncthreads();
  f32x4 zero = {0.f, 0.f, 0.f, 0.f};
  f32x4 s[8];
  for (int f = 0; f < 8; f++) {
    bf16x8 kf = *(bf16x8*)&Ks[16 * f + lrow][lk];
    s[f] = MFMA16(qf, kf, zero);
  }
  for (int rr = 0; rr < 4; rr++) {
    float m = s[0][rr];
    for (int f = 1; f < 8; f++) m = fmaxf(m, s[f][rr]);
    for (int off = 1; off < 16; off <<= 1) m = fmaxf(m, __shfl_xor(m, off));
    float sum = 0.f;
    for (int f = 0; f < 8; f++) { float p = __expf(s[f][rr] - m); s[f][rr] = p; sum += p; }
    for (int off = 1; off < 16; off <<= 1) sum += __shfl_xor(sum, off);
    float inv = 1.0f / sum;
    for (int f = 0; f < 8; f++) s[f][rr] *= inv;
  }
  for (int f = 0; f < 8; f++)
    for (int rr = 0; rr < 4; rr++)
      Ps[wid][(lane >> 4) * 4 + rr][16 * f + lrow] = (bf16)s[f][rr];
  __syncthreads();
  f32x4 o[2];
  o[0] = zero; o[1] = zero;
  for (int ks = 0; ks < 4; ks++) {
    bf16x8 pf = *(bf16x8*)&Ps[wid][lrow][ks * 32 + lk];
    for (int j = 0; j < 2; j++) {
      bf16x8 vf = *(bf16x8*)&Vs[16 * j + lrow][ks * 32 + lk];
      o[j] = MFMA16(pf, vf, o[j]);
    }
  }
  for (int j = 0; j < 2; j++) for (int rr = 0; rr < 4; rr++) {
    int nn = n0 + wid * 16 + (lane >> 4) * 4 + rr;
    out_att[((long)b * NSEQ + nn) * 192 + h * 32 + 16 * j + lrow] = (bf16)o[j][rr];
  }
}

// ---------------- proj GEMM: out(g,192) f32 = out_att(g,192) @ proj_w^T + proj_b (BK=96) ----------
__launch_bounds__(256)
__global__ void k_proj(const bf16* __restrict__ oa, const bf16* __restrict__ projw,
                       const float* __restrict__ proj_b, float* __restrict__ out) {
  __shared__ bf16 As[128][104];
  __shared__ bf16 Bs[64][104];
  int bn = blockIdx.x % 3;
  long g0 = (long)(blockIdx.x / 3) * 128;
  int n0 = bn * 64;
  int tid = threadIdx.x;
  int wid = tid >> 6, lane = tid & 63;
  int wm = wid >> 1, wn = wid & 1;
  int lrow = lane & 15, lk = (lane >> 4) * 8;
  int arow = tid >> 1, ahalf = (tid & 1) * 48;
  const bf16* Ap = oa + (g0 + arow) * 192 + ahalf;
  int brow = tid >> 2, bkoff = (tid & 3) * 24;
  const bf16* Bp = projw + (long)(n0 + brow) * 192 + bkoff;
  f32x4 zero = {0.f, 0.f, 0.f, 0.f};
  f32x4 acc[4][2];
  for (int i = 0; i < 4; i++) for (int j = 0; j < 2; j++) acc[i][j] = zero;
  for (int k0 = 0; k0 < 192; k0 += 96) {
    for (int m = 0; m < 6; m++)
      *(bf16x8*)&As[arow][ahalf + 8 * m] = *(const bf16x8*)(Ap + k0 + 8 * m);
    for (int m = 0; m < 3; m++)
      *(bf16x8*)&Bs[brow][bkoff + 8 * m] = *(const bf16x8*)(Bp + k0 + 8 * m);
    __syncthreads();
    for (int ks = 0; ks < 3; ks++) {
      bf16x8 af[4], bfv[2];
      for (int i = 0; i < 4; i++) af[i]  = *(bf16x8*)&As[wm * 64 + 16 * i + lrow][ks * 32 + lk];
      for (int j = 0; j < 2; j++) bfv[j] = *(bf16x8*)&Bs[wn * 32 + 16 * j + lrow][ks * 32 + lk];
      for (int i = 0; i < 4; i++) for (int j = 0; j < 2; j++) acc[i][j] = MFMA16(af[i], bfv[j], acc[i][j]);
    }
    __syncthreads();
  }
  for (int i = 0; i < 4; i++) for (int j = 0; j < 2; j++) for (int rr = 0; rr < 4; rr++) {
    long grow = g0 + wm * 64 + 16 * i + (lane >> 4) * 4 + rr;
    int c = n0 + wn * 32 + 16 * j + lrow;
    out[grow * 192 + c] = acc[i][j][rr] + proj_b[c];
  }
}

extern "C" void kernel_launch(void* const* d_in, const int* in_sizes, int n_in,
                              void* d_out, int out_size, void* d_ws, size_t ws_size,
                              hipStream_t stream) {
  const float* x      = (const float*)d_in[0];
  const float* qkv_w  = (const float*)d_in[1];
  const float* qkv_b  = (const float*)d_in[2];
  const float* E_w    = (const float*)d_in[3];
  const float* E_b    = (const float*)d_in[4];
  const float* F_w    = (const float*)d_in[5];
  const float* F_b    = (const float*)d_in[6];
  const float* proj_w = (const float*)d_in[7];
  const float* proj_b = (const float*)d_in[8];
  float* out = (float*)d_out;

  char* ws = (char*)d_ws;
  size_t off = 0;
  auto alloc = [&](size_t bytes) { char* p = ws + off; off += (bytes + 255) & ~(size_t)255; return p; };
  bf16* qkvw     = (bf16*)alloc((size_t)110592 * 2);
  bf16* EF       = (bf16*)alloc((size_t)802816 * 2);
  bf16* projw    = (bf16*)alloc((size_t)36864 * 2);
  float* rowsums = (float*)alloc((size_t)256 * 4);
  bf16* xmT      = (bf16*)alloc((size_t)32 * 192 * NSEQ * 2);   // reused as out_att after xlow
  float* partial = (float*)alloc((size_t)2688 * 4096 * 4);      // 44 MB; aliased by q below
  bf16* q        = (bf16*)partial;                              // lifetimes disjoint (qgemm after reduce)
  bf16* el_fl    = (bf16*)alloc((size_t)32 * 256 * 192 * 2);
  bf16* k_low    = (bf16*)alloc((size_t)32 * 128 * 192 * 2);
  bf16* v_lowT   = (bf16*)alloc((size_t)32 * 192 * 128 * 2);
  bf16* out_att  = xmT;

  k_convert<<<dim3(480), dim3(256), 0, stream>>>(qkv_w, E_w, F_w, proj_w, qkvw, EF, projw);
  k_rowsum<<<dim3(256), dim3(256), 0, stream>>>(E_w, F_w, rowsums);
  k_xT<<<dim3(32 * 98), dim3(192), 0, stream>>>(x, xmT);
  k_xlow<<<dim3(2688), dim3(256), 0, stream>>>(EF, xmT, partial);
  k_reduce<<<dim3(1536), dim3(256), 0, stream>>>(partial, el_fl);
  k_lowproj<<<dim3(384), dim3(256), 0, stream>>>(el_fl, qkvw, qkv_b, E_b, F_b, rowsums, k_low, v_lowT);
  k_qgemm<<<dim3(784 * 3), dim3(256), 0, stream>>>(x, qkvw, qkv_b, q);
  k_attn<<<dim3(32 * 6 * 49), dim3(256), 0, stream>>>(q, k_low, v_lowT, out_att);
  k_proj<<<dim3(784 * 3), dim3(256), 0, stream>>>(out_att, projw, proj_b, out);
}

// Round 3
// 327.886 us; speedup vs baseline: 1.0952x; 1.0411x over previous
//
#include <hip/hip_runtime.h>

typedef __bf16 bf16;
typedef bf16 bf16x8 __attribute__((ext_vector_type(8)));
typedef float f32x4 __attribute__((ext_vector_type(4)));

#define MFMA16(a,b,c) __builtin_amdgcn_mfma_f32_16x16x32_bf16(a,b,c,0,0,0)

#define NSEQ 3136
#define CDIM 192

__device__ inline bf16x8 cvt8(float4 a, float4 b) {
  bf16x8 r;
  r[0]=(bf16)a.x; r[1]=(bf16)a.y; r[2]=(bf16)a.z; r[3]=(bf16)a.w;
  r[4]=(bf16)b.x; r[5]=(bf16)b.y; r[6]=(bf16)b.z; r[7]=(bf16)b.w;
  return r;
}

// ---------------- weight conversion fp32 -> bf16 ----------------
__global__ void k_convert(const float* __restrict__ qkv_w, const float* __restrict__ E_w,
                          const float* __restrict__ F_w, const float* __restrict__ proj_w,
                          bf16* __restrict__ qkvw, bf16* __restrict__ EF, bf16* __restrict__ projw) {
  int i = blockIdx.x * blockDim.x + threadIdx.x;
  const int tot = 950272;
  for (; i < tot; i += gridDim.x * blockDim.x) {
    if (i < 110592) qkvw[i] = (bf16)qkv_w[i];
    else if (i < 512000) EF[i - 110592] = (bf16)E_w[i - 110592];
    else if (i < 913408) EF[i - 110592] = (bf16)F_w[i - 512000];
    else projw[i - 913408] = (bf16)proj_w[i - 913408];
  }
}

// rowsums[kr] = sum_n E_w[kr,n] (kr<128) or F_w[kr-128,n]
__global__ void k_rowsum(const float* __restrict__ E_w, const float* __restrict__ F_w,
                         float* __restrict__ rowsums) {
  __shared__ float red[4];
  int row = blockIdx.x; // 0..255
  const float* src = (row < 128) ? (E_w + (long)row * NSEQ) : (F_w + (long)(row - 128) * NSEQ);
  float s = 0.f;
  for (int i = threadIdx.x; i < NSEQ; i += 256) s += src[i];
  for (int off = 32; off; off >>= 1) s += __shfl_xor(s, off);
  if ((threadIdx.x & 63) == 0) red[threadIdx.x >> 6] = s;
  __syncthreads();
  if (threadIdx.x == 0) rowsums[row] = red[0] + red[1] + red[2] + red[3];
}

// ---------------- window_reverse + transpose: x (2048,49,192) f32 -> xmT (32,192,3136) bf16 --------
__global__ void k_xT(const float* __restrict__ x, bf16* __restrict__ xmT) {
  __shared__ bf16 tile[32][200];
  int blk = blockIdx.x;
  int b = blk / 98, n0 = (blk % 98) * 32;
  int c = threadIdx.x; // 0..191
  for (int i = 0; i < 32; ++i) {
    int n = n0 + i;
    int r = n / 56, cc = n % 56;
    long srcrow = ((long)(b * 64 + (r / 7) * 8 + (cc / 7)) * 49 + (r % 7) * 7 + (cc % 7));
    tile[i][c] = (bf16)x[srcrow * 192 + c];
  }
  __syncthreads();
  int nn = threadIdx.x & 31;
  int cb = threadIdx.x >> 5; // 0..5
  for (int i = 0; i < 32; ++i) {
    int c2 = cb + 6 * i;
    xmT[((long)b * 192 + c2) * NSEQ + n0 + nn] = tile[nn][c2];
  }
}

// ---------------- xlow GEMM split-K: partial[(b*12+t)*7+s] = [E;F]-tile @ xmT-tile^T over K-slice ---
__launch_bounds__(256)
__global__ void k_xlow(const bf16* __restrict__ EF, const bf16* __restrict__ xmT,
                       float* __restrict__ partial) {
  __shared__ bf16 As[64][72];
  __shared__ bf16 Bs[64][72];
  int idx = blockIdx.x;
  int s = idx % 7;
  int rem = (idx / 7) % 12;
  int b = idx / 84;
  int m0 = (rem / 3) * 64, n0 = (rem % 3) * 64;
  int kbase = s * 448;
  int tid = threadIdx.x;
  int wid = tid >> 6, lane = tid & 63;
  int wm = wid >> 1, wn = wid & 1;
  int lrow = lane & 15, lk = (lane >> 4) * 8;
  int srow = tid >> 2, skoff = (tid & 3) * 16;
  const bf16* Ap = EF + (long)(m0 + srow) * NSEQ + kbase + skoff;
  const bf16* Bp = xmT + ((long)b * 192 + n0 + srow) * NSEQ + kbase + skoff;
  f32x4 zero = {0.f, 0.f, 0.f, 0.f};
  f32x4 acc[2][2];
  for (int i = 0; i < 2; i++) for (int j = 0; j < 2; j++) acc[i][j] = zero;
  for (int k0 = 0; k0 < 448; k0 += 64) {
    *(bf16x8*)&As[srow][skoff]     = *(const bf16x8*)(Ap + k0);
    *(bf16x8*)&As[srow][skoff + 8] = *(const bf16x8*)(Ap + k0 + 8);
    *(bf16x8*)&Bs[srow][skoff]     = *(const bf16x8*)(Bp + k0);
    *(bf16x8*)&Bs[srow][skoff + 8] = *(const bf16x8*)(Bp + k0 + 8);
    __syncthreads();
    for (int ks = 0; ks < 2; ks++) {
      bf16x8 af[2], bfv[2];
      for (int i = 0; i < 2; i++) af[i]  = *(bf16x8*)&As[wm * 32 + 16 * i + lrow][ks * 32 + lk];
      for (int j = 0; j < 2; j++) bfv[j] = *(bf16x8*)&Bs[wn * 32 + 16 * j + lrow][ks * 32 + lk];
      for (int i = 0; i < 2; i++) for (int j = 0; j < 2; j++) acc[i][j] = MFMA16(af[i], bfv[j], acc[i][j]);
    }
    __syncthreads();
  }
  float* P = partial + (long)idx * 4096;
  for (int i = 0; i < 2; i++) for (int j = 0; j < 2; j++) for (int rr = 0; rr < 4; rr++) {
    int rl = wm * 32 + 16 * i + (lane >> 4) * 4 + rr;
    int cl = wn * 32 + 16 * j + lrow;
    P[rl * 64 + cl] = acc[i][j][rr];
  }
}

// ---------------- reduce 7 split-K partials -> el_fl (b,256,192) bf16 ------------------------------
__global__ void k_reduce(const float* __restrict__ partial, bf16* __restrict__ el_fl) {
  int idx = blockIdx.x;          // 32*12*4
  int qtr = idx & 3;
  int bt = idx >> 2;             // b*12 + t
  int t = bt % 12, b = bt / 12;
  const float* P = partial + (long)bt * 7 * 4096 + qtr * 1024;
  for (int i = 0; i < 4; i++) {
    int e = i * 256 + threadIdx.x;
    float sum = 0.f;
    for (int s = 0; s < 7; s++) sum += P[s * 4096 + e];
    int ee = qtr * 1024 + e;
    int lm = ee >> 6, lc = ee & 63;
    int kr = (t / 3) * 64 + lm, c = (t % 3) * 64 + lc;
    el_fl[((long)b * 256 + kr) * 192 + c] = (bf16)sum;
  }
}

// ---------------- low-rank proj: k_low = el@Wk^T + bias ; v_lowT = Wv@fl^T + bias (K=192 1-stage) --
__launch_bounds__(256)
__global__ void k_lowproj(const bf16* __restrict__ el_fl, const bf16* __restrict__ qkvw,
                          const float* __restrict__ qkv_b, const float* __restrict__ E_b,
                          const float* __restrict__ F_b, const float* __restrict__ rowsums,
                          bf16* __restrict__ k_low, bf16* __restrict__ v_lowT) {
  __shared__ bf16 As[64][200];
  __shared__ bf16 Bs[64][200];
  int idx = blockIdx.x;
  int b = idx / 12, rem = idx % 12;
  int type = rem / 6; rem %= 6;
  int bm, bn;
  if (type == 0) { bm = rem / 3; bn = rem % 3; }
  else           { bm = rem / 2; bn = rem % 2; }
  int m0 = bm * 64, n0 = bn * 64;
  int tid = threadIdx.x;
  int wid = tid >> 6, lane = tid & 63;
  int wm = wid >> 1, wn = wid & 1;
  int lrow = lane & 15, lk = (lane >> 4) * 8;
  int srow = tid >> 2, skoff = (tid & 3) * 16;
  const bf16* Ap; const bf16* Bp;
  if (type == 0) {
    Ap = el_fl + ((long)b * 256 + m0 + srow) * 192 + skoff;
    Bp = qkvw + (long)(192 + n0 + srow) * 192 + skoff;
  } else {
    Ap = qkvw + (long)(384 + m0 + srow) * 192 + skoff;
    Bp = el_fl + ((long)b * 256 + 128 + n0 + srow) * 192 + skoff;
  }
  for (int kk = 0; kk < 192; kk += 64) {
    *(bf16x8*)&As[srow][kk + skoff]     = *(const bf16x8*)(Ap + kk);
    *(bf16x8*)&As[srow][kk + skoff + 8] = *(const bf16x8*)(Ap + kk + 8);
    *(bf16x8*)&Bs[srow][kk + skoff]     = *(const bf16x8*)(Bp + kk);
    *(bf16x8*)&Bs[srow][kk + skoff + 8] = *(const bf16x8*)(Bp + kk + 8);
  }
  __syncthreads();
  f32x4 zero = {0.f, 0.f, 0.f, 0.f};
  f32x4 acc[2][2];
  for (int i = 0; i < 2; i++) for (int j = 0; j < 2; j++) acc[i][j] = zero;
  for (int ks = 0; ks < 6; ks++) {
    bf16x8 af[2], bfv[2];
    for (int i = 0; i < 2; i++) af[i]  = *(bf16x8*)&As[wm * 32 + 16 * i + lrow][ks * 32 + lk];
    for (int j = 0; j < 2; j++) bfv[j] = *(bf16x8*)&Bs[wn * 32 + 16 * j + lrow][ks * 32 + lk];
    for (int i = 0; i < 2; i++) for (int j = 0; j < 2; j++) acc[i][j] = MFMA16(af[i], bfv[j], acc[i][j]);
  }
  if (type == 0) {
    for (int i = 0; i < 2; i++) for (int j = 0; j < 2; j++) for (int rr = 0; rr < 4; rr++) {
      int kr = m0 + wm * 32 + 16 * i + (lane >> 4) * 4 + rr;
      int c = n0 + wn * 32 + 16 * j + lrow;
      float v = acc[i][j][rr] + rowsums[kr] * qkv_b[192 + c] + E_b[kr];
      k_low[((long)b * 128 + kr) * 192 + c] = (bf16)v;
    }
  } else {
    for (int i = 0; i < 2; i++) for (int j = 0; j < 2; j++) for (int rr = 0; rr < 4; rr++) {
      int c = m0 + wm * 32 + 16 * i + (lane >> 4) * 4 + rr;
      int kr = n0 + wn * 32 + 16 * j + lrow;
      float v = acc[i][j][rr] + rowsums[128 + kr] * qkv_b[384 + c] + F_b[kr];
      v_lowT[((long)b * 192 + c) * 128 + kr] = (bf16)v;
    }
  }
}

// ---------------- Q GEMM full-N: q(128 rows, all 192 cols) per block; Wq LDS-resident --------------
__launch_bounds__(256)
__global__ void k_qgemm(const float* __restrict__ x, const bf16* __restrict__ qkvw,
                        const float* __restrict__ qkv_b, bf16* __restrict__ q) {
  __shared__ bf16 As[128][104];
  __shared__ bf16 Bs[192][104];
  long g0 = (long)blockIdx.x * 128;
  int tid = threadIdx.x;
  int wid = tid >> 6, lane = tid & 63;
  int lrow = lane & 15, lk = (lane >> 4) * 8;
  // B staging: full Wq (192x192) once
  {
    int koff = (tid & 3) * 48;
    for (int r0 = 0; r0 < 192; r0 += 64) {
      int row = r0 + (tid >> 2);
      const bf16* Bp = qkvw + (long)row * 192 + koff;
      for (int m = 0; m < 6; m++)
        *(bf16x8*)&Bs[row][((koff + 8 * m) % 96) + (koff >= 96 ? 96 : 0)] = *(const bf16x8*)(Bp + 8 * m);
    }
  }
  // A address (window_reverse gather)
  int arow = tid >> 1, half = tid & 1;
  long g = g0 + arow;
  int b = (int)(g / NSEQ), n = (int)(g % NSEQ);
  int r = n / 56, cc = n % 56;
  long srcrow = (long)(b * 64 + (r / 7) * 8 + (cc / 7)) * 49 + (r % 7) * 7 + (cc % 7);
  const float* Ap = x + srcrow * 192 + half * 48;
  f32x4 zero = {0.f, 0.f, 0.f, 0.f};
  f32x4 acc[2][12];
  for (int i = 0; i < 2; i++) for (int j = 0; j < 12; j++) acc[i][j] = zero;
  for (int k0 = 0; k0 < 192; k0 += 96) {
    for (int m = 0; m < 3; m++) {
      const float4* xp = (const float4*)(Ap + k0 + 16 * m);
      float4 f0 = xp[0], f1 = xp[1];
      *(bf16x8*)&As[arow][half * 48 + 16 * m] = cvt8(f0, f1);
      float4 f2 = xp[2], f3 = xp[3];
      *(bf16x8*)&As[arow][half * 48 + 16 * m + 8] = cvt8(f2, f3);
    }
    __syncthreads();
    for (int ks = 0; ks < 3; ks++) {
      bf16x8 af[2];
      for (int i = 0; i < 2; i++) af[i] = *(bf16x8*)&As[wid * 32 + 16 * i + lrow][ks * 32 + lk];
      for (int j = 0; j < 12; j++) {
        bf16x8 bfv = *(bf16x8*)&Bs[16 * j + lrow][(k0 / 2) + ks * 16 + (lk / 2) + (lk & 4) * 12];
        // NOTE: replaced below by simple layout; see Bs addressing comment
        (void)bfv;
      }
      // simple layout version (Bs holds K contiguous 0..191 across two 48-col halves):
      for (int j = 0; j < 12; j++) {
        bf16x8 bv = *(bf16x8*)&Bs[16 * j + lrow][0];
        (void)bv; // placeholder, real code below
      }
      (void)ks;
    }
    __syncthreads();
  }
  // --- real implementation below (the above placeholder loop is dead code) ---
  // (kept minimal: recompute properly)
  for (int i = 0; i < 2; i++) for (int j = 0; j < 12; j++) acc[i][j] = zero;
  __syncthreads();
  for (int k0 = 0; k0 < 192; k0 += 96) {
    for (int m = 0; m < 3; m++) {
      const float4* xp = (const float4*)(Ap + k0 + 16 * m);
      float4 f0 = xp[0], f1 = xp[1];
      *(bf16x8*)&As[arow][half * 48 + 16 * m] = cvt8(f0, f1);
      float4 f2 = xp[2], f3 = xp[3];
      *(bf16x8*)&As[arow][half * 48 + 16 * m + 8] = cvt8(f2, f3);
    }
    __syncthreads();
    for (int ks = 0; ks < 3; ks++) {
      bf16x8 af[2];
      for (int i = 0; i < 2; i++) af[i] = *(bf16x8*)&As[wid * 32 + 16 * i + lrow][ks * 32 + lk];
      for (int j = 0; j < 12; j++) {
        bf16x8 bv = *(bf16x8*)&Bs[16 * j + lrow][k0 + ks * 32 + lk - k0 + (k0 ? 0 : 0)];
        (void)bv;
      }
    }
    __syncthreads();
  }
  // fallthrough store of zeros would be wrong — this path is never taken; see k_qgemm2
  (void)acc;
}

// Clean full-N Q GEMM (the one actually launched)
__launch_bounds__(256)
__global__ void k_qgemm2(const float* __restrict__ x, const bf16* __restrict__ qkvw,
                         const float* __restrict__ qkv_b, bf16* __restrict__ q) {
  __shared__ bf16 As[128][104];   // current K-chunk of A (128 x 96)
  __shared__ bf16 Bs[192][200];   // full Wq: row = out col c, 192 K entries
  long g0 = (long)blockIdx.x * 128;
  int tid = threadIdx.x;
  int wid = tid >> 6, lane = tid & 63;
  int lrow = lane & 15, lk = (lane >> 4) * 8;
  // stage full Wq
  {
    int koff = (tid & 3) * 48;
    for (int r0 = 0; r0 < 192; r0 += 64) {
      int row = r0 + (tid >> 2);
      const bf16* Bp = qkvw + (long)row * 192 + koff;
      for (int m = 0; m < 6; m++)
        *(bf16x8*)&Bs[row][koff + 8 * m] = *(const bf16x8*)(Bp + 8 * m);
    }
  }
  int arow = tid >> 1, half = tid & 1;
  long g = g0 + arow;
  int b = (int)(g / NSEQ), n = (int)(g % NSEQ);
  int r = n / 56, cc = n % 56;
  long srcrow = (long)(b * 64 + (r / 7) * 8 + (cc / 7)) * 49 + (r % 7) * 7 + (cc % 7);
  const float* Ap = x + srcrow * 192 + half * 48;
  f32x4 zero = {0.f, 0.f, 0.f, 0.f};
  f32x4 acc[2][12];
  for (int i = 0; i < 2; i++) for (int j = 0; j < 12; j++) acc[i][j] = zero;
  for (int k0 = 0; k0 < 192; k0 += 96) {
    for (int m = 0; m < 3; m++) {
      const float4* xp = (const float4*)(Ap + k0 + 16 * m);
      float4 f0 = xp[0], f1 = xp[1];
      float4 f2 = xp[2], f3 = xp[3];
      *(bf16x8*)&As[arow][half * 48 + 16 * m] = cvt8(f0, f1);
      *(bf16x8*)&As[arow][half * 48 + 16 * m + 8] = cvt8(f2, f3);
    }
    __syncthreads();
    for (int ks = 0; ks < 3; ks++) {
      bf16x8 af[2];
      for (int i = 0; i < 2; i++) af[i] = *(bf16x8*)&As[wid * 32 + 16 * i + lrow][ks * 32 + lk];
      for (int j = 0; j < 12; j++) {
        bf16x8 bv = *(bf16x8*)&Bs[16 * j + lrow][k0 + ks * 32 + lk];
        acc[0][j] = MFMA16(af[0], bv, acc[0][j]);
        acc[1][j] = MFMA16(af[1], bv, acc[1][j]);
      }
    }
    __syncthreads();
  }
  const float scale = 0.17677669529663687f; // 1/sqrt(32)
  for (int i = 0; i < 2; i++) for (int j = 0; j < 12; j++) for (int rr = 0; rr < 4; rr++) {
    long grow = g0 + wid * 32 + 16 * i + (lane >> 4) * 4 + rr;
    int c = 16 * j + lrow;
    float v = (acc[i][j][rr] + qkv_b[c]) * scale;
    q[grow * 192 + c] = (bf16)v;
  }
}

// ---------------- fused attention: per (b,h,64-row tile): S = q@k_low^T, softmax, O = P@v_low -----
__launch_bounds__(256)
__global__ void k_attn(const bf16* __restrict__ q, const bf16* __restrict__ k_low,
                       const bf16* __restrict__ v_lowT, bf16* __restrict__ out_att) {
  __shared__ bf16 Ks[128][40];
  __shared__ bf16 Vs[32][136];
  __shared__ bf16 Ps[4][16][136];
  int idx = blockIdx.x;
  int nt = idx % 49, bh = idx / 49;
  int h = bh % 6, b = bh / 6;
  int n0 = nt * 64;
  int tid = threadIdx.x;
  int wid = tid >> 6, lane = tid & 63;
  int lrow = lane & 15, lk = (lane >> 4) * 8;
  {
    int row = tid >> 1, koff = (tid & 1) * 16;
    const bf16* src = k_low + ((long)b * 128 + row) * 192 + h * 32 + koff;
    *(bf16x8*)&Ks[row][koff] = *(const bf16x8*)src;
    *(bf16x8*)&Ks[row][koff + 8] = *(const bf16x8*)(src + 8);
  }
  {
    int row = tid >> 3, koff = (tid & 7) * 16;
    const bf16* src = v_lowT + ((long)b * 192 + h * 32 + row) * 128 + koff;
    *(bf16x8*)&Vs[row][koff] = *(const bf16x8*)src;
    *(bf16x8*)&Vs[row][koff + 8] = *(const bf16x8*)(src + 8);
  }
  int nrow = n0 + wid * 16 + lrow;
  bf16x8 qf = *(const bf16x8*)(q + ((long)b * NSEQ + nrow) * 192 + h * 32 + lk);
  __syncthreads();
  f32x4 zero = {0.f, 0.f, 0.f, 0.f};
  f32x4 s[8];
  for (int f = 0; f < 8; f++) {
    bf16x8 kf = *(bf16x8*)&Ks[16 * f + lrow][lk];
    s[f] = MFMA16(qf, kf, zero);
  }
  for (int rr = 0; rr < 4; rr++) {
    float m = s[0][rr];
    for (int f = 1; f < 8; f++) m = fmaxf(m, s[f][rr]);
    for (int off = 1; off < 16; off <<= 1) m = fmaxf(m, __shfl_xor(m, off));
    float sum = 0.f;
    for (int f = 0; f < 8; f++) { float p = __expf(s[f][rr] - m); s[f][rr] = p; sum += p; }
    for (int off = 1; off < 16; off <<= 1) sum += __shfl_xor(sum, off);
    float inv = 1.0f / sum;
    for (int f = 0; f < 8; f++) s[f][rr] *= inv;
  }
  for (int f = 0; f < 8; f++)
    for (int rr = 0; rr < 4; rr++)
      Ps[wid][(lane >> 4) * 4 + rr][16 * f + lrow] = (bf16)s[f][rr];
  __syncthreads();
  f32x4 o[2];
  o[0] = zero; o[1] = zero;
  for (int ks = 0; ks < 4; ks++) {
    bf16x8 pf = *(bf16x8*)&Ps[wid][lrow][ks * 32 + lk];
    for (int j = 0; j < 2; j++) {
      bf16x8 vf = *(bf16x8*)&Vs[16 * j + lrow][ks * 32 + lk];
      o[j] = MFMA16(pf, vf, o[j]);
    }
  }
  for (int j = 0; j < 2; j++) for (int rr = 0; rr < 4; rr++) {
    int nn = n0 + wid * 16 + (lane >> 4) * 4 + rr;
    out_att[((long)b * NSEQ + nn) * 192 + h * 32 + 16 * j + lrow] = (bf16)o[j][rr];
  }
}

// ---------------- proj GEMM full-N: out(128 rows, all 192 cols) fp32; projw LDS-resident -----------
__launch_bounds__(256)
__global__ void k_proj(const bf16* __restrict__ oa, const bf16* __restrict__ projw,
                       const float* __restrict__ proj_b, float* __restrict__ out) {
  __shared__ bf16 As[128][104];
  __shared__ bf16 Bs[192][200];
  long g0 = (long)blockIdx.x * 128;
  int tid = threadIdx.x;
  int wid = tid >> 6, lane = tid & 63;
  int lrow = lane & 15, lk = (lane >> 4) * 8;
  {
    int koff = (tid & 3) * 48;
    for (int r0 = 0; r0 < 192; r0 += 64) {
      int row = r0 + (tid >> 2);
      const bf16* Bp = projw + (long)row * 192 + koff;
      for (int m = 0; m < 6; m++)
        *(bf16x8*)&Bs[row][koff + 8 * m] = *(const bf16x8*)(Bp + 8 * m);
    }
  }
  int arow = tid >> 1, half = tid & 1;
  const bf16* Ap = oa + (g0 + arow) * 192 + half * 48;
  f32x4 zero = {0.f, 0.f, 0.f, 0.f};
  f32x4 acc[2][12];
  for (int i = 0; i < 2; i++) for (int j = 0; j < 12; j++) acc[i][j] = zero;
  for (int k0 = 0; k0 < 192; k0 += 96) {
    for (int m = 0; m < 6; m++)
      *(bf16x8*)&As[arow][half * 48 + 8 * m] = *(const bf16x8*)(Ap + k0 + 8 * m);
    __syncthreads();
    for (int ks = 0; ks < 3; ks++) {
      bf16x8 af[2];
      for (int i = 0; i < 2; i++) af[i] = *(bf16x8*)&As[wid * 32 + 16 * i + lrow][ks * 32 + lk];
      for (int j = 0; j < 12; j++) {
        bf16x8 bv = *(bf16x8*)&Bs[16 * j + lrow][k0 + ks * 32 + lk];
        acc[0][j] = MFMA16(af[0], bv, acc[0][j]);
        acc[1][j] = MFMA16(af[1], bv, acc[1][j]);
      }
    }
    __syncthreads();
  }
  for (int i = 0; i < 2; i++) for (int j = 0; j < 12; j++) for (int rr = 0; rr < 4; rr++) {
    long grow = g0 + wid * 32 + 16 * i + (lane >> 4) * 4 + rr;
    int c = 16 * j + lrow;
    out[grow * 192 + c] = acc[i][j][rr] + proj_b[c];
  }
}

extern "C" void kernel_launch(void* const* d_in, const int* in_sizes, int n_in,
                              void* d_out, int out_size, void* d_ws, size_t ws_size,
                              hipStream_t stream) {
  const float* x      = (const float*)d_in[0];
  const float* qkv_w  = (const float*)d_in[1];
  const float* qkv_b  = (const float*)d_in[2];
  const float* E_w    = (const float*)d_in[3];
  const float* E_b    = (const float*)d_in[4];
  const float* F_w    = (const float*)d_in[5];
  const float* F_b    = (const float*)d_in[6];
  const float* proj_w = (const float*)d_in[7];
  const float* proj_b = (const float*)d_in[8];
  float* out = (float*)d_out;

  char* ws = (char*)d_ws;
  size_t off = 0;
  auto alloc = [&](size_t bytes) { char* p = ws + off; off += (bytes + 255) & ~(size_t)255; return p; };
  bf16* qkvw     = (bf16*)alloc((size_t)110592 * 2);
  bf16* EF       = (bf16*)alloc((size_t)802816 * 2);
  bf16* projw    = (bf16*)alloc((size_t)36864 * 2);
  float* rowsums = (float*)alloc((size_t)256 * 4);
  bf16* xmT      = (bf16*)alloc((size_t)32 * 192 * NSEQ * 2);   // reused as out_att after xlow
  float* partial = (float*)alloc((size_t)2688 * 4096 * 4);      // 44 MB; aliased by q below
  bf16* q        = (bf16*)partial;                              // lifetimes disjoint (qgemm after reduce)
  bf16* el_fl    = (bf16*)alloc((size_t)32 * 256 * 192 * 2);
  bf16* k_low    = (bf16*)alloc((size_t)32 * 128 * 192 * 2);
  bf16* v_lowT   = (bf16*)alloc((size_t)32 * 192 * 128 * 2);
  bf16* out_att  = xmT;

  k_convert<<<dim3(480), dim3(256), 0, stream>>>(qkv_w, E_w, F_w, proj_w, qkvw, EF, projw);
  k_rowsum<<<dim3(256), dim3(256), 0, stream>>>(E_w, F_w, rowsums);
  k_xT<<<dim3(32 * 98), dim3(192), 0, stream>>>(x, xmT);
  k_xlow<<<dim3(2688), dim3(256), 0, stream>>>(EF, xmT, partial);
  k_reduce<<<dim3(1536), dim3(256), 0, stream>>>(partial, el_fl);
  k_lowproj<<<dim3(384), dim3(256), 0, stream>>>(el_fl, qkvw, qkv_b, E_b, F_b, rowsums, k_low, v_lowT);
  k_qgemm2<<<dim3(784), dim3(256), 0, stream>>>(x, qkvw, qkv_b, q);
  k_attn<<<dim3(32 * 6 * 49), dim3(256), 0, stream>>>(q, k_low, v_lowT, out_att);
  k_proj<<<dim3(784), dim3(256), 0, stream>>>(out_att, projw, proj_b, out);
}